// Round 1
// baseline (3082.720 us; speedup 1.0000x reference)
//
#include <hip/hip_runtime.h>
#include <math.h>

// Problem dims (fixed by reference)
constexpr int kB = 16;
constexpr int kT = 1024;
constexpr int kS = 2048;
constexpr int kH = 1024;

// SGEMM tiling: 128x128 block tile, BK=16, 256 threads, 8x8 per thread.
constexpr int BM = 128;
constexpr int BN = 128;
constexpr int BK = 16;
constexpr int LDP = BM + 4;  // padded LDS stride (banks: +4 breaks 128-stride conflicts)

// ---------------------------------------------------------------------------
// NT GEMM: C[M,N] = A[M,K] * B[N,K]^T   (both operands K-contiguous, row-major)
// Batched via blockIdx.z with element strides.
// ---------------------------------------------------------------------------
__global__ __launch_bounds__(256) void gemm_nt(
    const float* __restrict__ A, int lda, long strideA,
    const float* __restrict__ Bm, int ldb, long strideB,
    float* __restrict__ C, int ldc, long strideC,
    int K)
{
    A  += strideA * (long)blockIdx.z;
    Bm += strideB * (long)blockIdx.z;
    C  += strideC * (long)blockIdx.z;
    const int bm = blockIdx.y * BM;
    const int bn = blockIdx.x * BN;

    __shared__ __align__(16) float As[BK][LDP];
    __shared__ __align__(16) float Bs[BK][LDP];

    const int t    = threadIdx.x;          // 0..255
    const int lrow = t >> 2;               // 0..63
    const int lcol = (t & 3) << 2;         // 0,4,8,12
    const int ty   = t >> 4;               // 0..15
    const int tx   = t & 15;               // 0..15

    float acc[8][8] = {};

    for (int k0 = 0; k0 < K; k0 += BK) {
#pragma unroll
        for (int r = 0; r < 2; ++r) {
            const int row = lrow + r * 64;
            float4 va = *(const float4*)(A + (long)(bm + row) * lda + (k0 + lcol));
            As[lcol + 0][row] = va.x;
            As[lcol + 1][row] = va.y;
            As[lcol + 2][row] = va.z;
            As[lcol + 3][row] = va.w;
            float4 vb = *(const float4*)(Bm + (long)(bn + row) * ldb + (k0 + lcol));
            Bs[lcol + 0][row] = vb.x;
            Bs[lcol + 1][row] = vb.y;
            Bs[lcol + 2][row] = vb.z;
            Bs[lcol + 3][row] = vb.w;
        }
        __syncthreads();
#pragma unroll
        for (int k = 0; k < BK; ++k) {
            float a[8], b[8];
            *(float4*)(&a[0]) = *(const float4*)(&As[k][ty * 8]);
            *(float4*)(&a[4]) = *(const float4*)(&As[k][ty * 8 + 4]);
            *(float4*)(&b[0]) = *(const float4*)(&Bs[k][tx * 8]);
            *(float4*)(&b[4]) = *(const float4*)(&Bs[k][tx * 8 + 4]);
#pragma unroll
            for (int i = 0; i < 8; ++i)
#pragma unroll
                for (int j = 0; j < 8; ++j)
                    acc[i][j] = fmaf(a[i], b[j], acc[i][j]);
        }
        __syncthreads();
    }

#pragma unroll
    for (int i = 0; i < 8; ++i) {
        float* crow = C + (long)(bm + ty * 8 + i) * ldc + bn + tx * 8;
        *(float4*)(crow)     = make_float4(acc[i][0], acc[i][1], acc[i][2], acc[i][3]);
        *(float4*)(crow + 4) = make_float4(acc[i][4], acc[i][5], acc[i][6], acc[i][7]);
    }
}

// ---------------------------------------------------------------------------
// NN GEMM: C[M,N] = A[M,K] * B[K,N]   (A K-contiguous, B N-contiguous)
// ---------------------------------------------------------------------------
__global__ __launch_bounds__(256) void gemm_nn(
    const float* __restrict__ A, int lda, long strideA,
    const float* __restrict__ Bm, int ldb, long strideB,
    float* __restrict__ C, int ldc, long strideC,
    int K)
{
    A  += strideA * (long)blockIdx.z;
    Bm += strideB * (long)blockIdx.z;
    C  += strideC * (long)blockIdx.z;
    const int bm = blockIdx.y * BM;
    const int bn = blockIdx.x * BN;

    __shared__ __align__(16) float As[BK][LDP];
    __shared__ __align__(16) float Bs[BK][LDP];

    const int t    = threadIdx.x;
    const int lrow = t >> 2;               // A: 0..63
    const int lcol = (t & 3) << 2;
    const int krow = t >> 5;               // B: 0..7
    const int ncol = (t & 31) << 2;        // 0..124
    const int ty   = t >> 4;
    const int tx   = t & 15;

    float acc[8][8] = {};

    for (int k0 = 0; k0 < K; k0 += BK) {
#pragma unroll
        for (int r = 0; r < 2; ++r) {
            const int row = lrow + r * 64;
            float4 va = *(const float4*)(A + (long)(bm + row) * lda + (k0 + lcol));
            As[lcol + 0][row] = va.x;
            As[lcol + 1][row] = va.y;
            As[lcol + 2][row] = va.z;
            As[lcol + 3][row] = va.w;
            const int kk = krow + r * 8;
            float4 vb = *(const float4*)(Bm + (long)(k0 + kk) * ldb + bn + ncol);
            *(float4*)(&Bs[kk][ncol]) = vb;
        }
        __syncthreads();
#pragma unroll
        for (int k = 0; k < BK; ++k) {
            float a[8], b[8];
            *(float4*)(&a[0]) = *(const float4*)(&As[k][ty * 8]);
            *(float4*)(&a[4]) = *(const float4*)(&As[k][ty * 8 + 4]);
            *(float4*)(&b[0]) = *(const float4*)(&Bs[k][tx * 8]);
            *(float4*)(&b[4]) = *(const float4*)(&Bs[k][tx * 8 + 4]);
#pragma unroll
            for (int i = 0; i < 8; ++i)
#pragma unroll
                for (int j = 0; j < 8; ++j)
                    acc[i][j] = fmaf(a[i], b[j], acc[i][j]);
        }
        __syncthreads();
    }

#pragma unroll
    for (int i = 0; i < 8; ++i) {
        float* crow = C + (long)(bm + ty * 8 + i) * ldc + bn + tx * 8;
        *(float4*)(crow)     = make_float4(acc[i][0], acc[i][1], acc[i][2], acc[i][3]);
        *(float4*)(crow + 4) = make_float4(acc[i][4], acc[i][5], acc[i][6], acc[i][7]);
    }
}

// ---------------------------------------------------------------------------
// Output projection: out[m,n] = tanh( sum_k [mix|q][m,k] * W[n,k] + bias[n] )
// M = B*T, N = H, K = 2H. A rows assembled from mix (k<H) and q (k>=H).
// ---------------------------------------------------------------------------
__global__ __launch_bounds__(256) void gemm_out(
    const float* __restrict__ Mix, const float* __restrict__ Q,
    const float* __restrict__ W, const float* __restrict__ bias,
    float* __restrict__ Out)
{
    const int bm = blockIdx.y * BM;
    const int bn = blockIdx.x * BN;

    __shared__ __align__(16) float As[BK][LDP];
    __shared__ __align__(16) float Bs[BK][LDP];

    const int t    = threadIdx.x;
    const int lrow = t >> 2;
    const int lcol = (t & 3) << 2;
    const int ty   = t >> 4;
    const int tx   = t & 15;

    float acc[8][8] = {};

    for (int k0 = 0; k0 < 2 * kH; k0 += BK) {
        // BK=16 divides H, so each k-tile is entirely in mix or entirely in q.
        const float* Asrc;
        int kk;
        if (k0 < kH) { Asrc = Mix; kk = k0; } else { Asrc = Q; kk = k0 - kH; }
#pragma unroll
        for (int r = 0; r < 2; ++r) {
            const int row = lrow + r * 64;
            float4 va = *(const float4*)(Asrc + (long)(bm + row) * kH + (kk + lcol));
            As[lcol + 0][row] = va.x;
            As[lcol + 1][row] = va.y;
            As[lcol + 2][row] = va.z;
            As[lcol + 3][row] = va.w;
            float4 vb = *(const float4*)(W + (long)(bn + row) * (2 * kH) + (k0 + lcol));
            Bs[lcol + 0][row] = vb.x;
            Bs[lcol + 1][row] = vb.y;
            Bs[lcol + 2][row] = vb.z;
            Bs[lcol + 3][row] = vb.w;
        }
        __syncthreads();
#pragma unroll
        for (int k = 0; k < BK; ++k) {
            float a[8], b[8];
            *(float4*)(&a[0]) = *(const float4*)(&As[k][ty * 8]);
            *(float4*)(&a[4]) = *(const float4*)(&As[k][ty * 8 + 4]);
            *(float4*)(&b[0]) = *(const float4*)(&Bs[k][tx * 8]);
            *(float4*)(&b[4]) = *(const float4*)(&Bs[k][tx * 8 + 4]);
#pragma unroll
            for (int i = 0; i < 8; ++i)
#pragma unroll
                for (int j = 0; j < 8; ++j)
                    acc[i][j] = fmaf(a[i], b[j], acc[i][j]);
        }
        __syncthreads();
    }

#pragma unroll
    for (int i = 0; i < 8; ++i) {
        float* crow = Out + (long)(bm + ty * 8 + i) * kH + bn + tx * 8;
        float o[8];
#pragma unroll
        for (int j = 0; j < 8; ++j)
            o[j] = tanhf(acc[i][j] + bias[bn + tx * 8 + j]);
        *(float4*)(crow)     = make_float4(o[0], o[1], o[2], o[3]);
        *(float4*)(crow + 4) = make_float4(o[4], o[5], o[6], o[7]);
    }
}

// ---------------------------------------------------------------------------
// In-place row softmax over S=2048, one block (256 threads) per row.
// ---------------------------------------------------------------------------
__global__ __launch_bounds__(256) void softmax_rows(float* __restrict__ P)
{
    __shared__ float red[4];
    float* p = P + (long)blockIdx.x * kS;
    const int t = threadIdx.x;

    float4 v0 = ((const float4*)p)[t];
    float4 v1 = ((const float4*)p)[t + 256];

    float m = fmaxf(fmaxf(fmaxf(v0.x, v0.y), fmaxf(v0.z, v0.w)),
                    fmaxf(fmaxf(v1.x, v1.y), fmaxf(v1.z, v1.w)));
#pragma unroll
    for (int o = 32; o > 0; o >>= 1) m = fmaxf(m, __shfl_xor(m, o));
    if ((t & 63) == 0) red[t >> 6] = m;
    __syncthreads();
    m = fmaxf(fmaxf(red[0], red[1]), fmaxf(red[2], red[3]));
    __syncthreads();

    v0.x = expf(v0.x - m); v0.y = expf(v0.y - m);
    v0.z = expf(v0.z - m); v0.w = expf(v0.w - m);
    v1.x = expf(v1.x - m); v1.y = expf(v1.y - m);
    v1.z = expf(v1.z - m); v1.w = expf(v1.w - m);

    float s = v0.x + v0.y + v0.z + v0.w + v1.x + v1.y + v1.z + v1.w;
#pragma unroll
    for (int o = 32; o > 0; o >>= 1) s += __shfl_xor(s, o);
    if ((t & 63) == 0) red[t >> 6] = s;
    __syncthreads();
    s = red[0] + red[1] + red[2] + red[3];

    const float inv = 1.0f / s;
    v0.x *= inv; v0.y *= inv; v0.z *= inv; v0.w *= inv;
    v1.x *= inv; v1.y *= inv; v1.z *= inv; v1.w *= inv;

    ((float4*)p)[t]       = v0;
    ((float4*)p)[t + 256] = v1;
}

// ---------------------------------------------------------------------------
extern "C" void kernel_launch(void* const* d_in, const int* in_sizes, int n_in,
                              void* d_out, int out_size, void* d_ws, size_t ws_size,
                              hipStream_t stream)
{
    (void)in_sizes; (void)n_in; (void)out_size; (void)ws_size;

    const float* output  = (const float*)d_in[0];   // [B,T,H]
    const float* context = (const float*)d_in[1];   // [B,S,H]
    const float* attn_w  = (const float*)d_in[2];   // [H,H]
    const float* lw      = (const float*)d_in[3];   // [H,2H]
    const float* lb      = (const float*)d_in[4];   // [H]

    float* out  = (float*)d_out;                          // [B,T,H]
    float* attn = (float*)d_out + (size_t)kB * kT * kH;   // [B,T,S]

    float* q   = (float*)d_ws;                            // [B,T,H]  64 MB
    float* mix = q + (size_t)kB * kT * kH;                // [B,T,H]  64 MB

    // 1) q = output @ attn_w^T : M=B*T=16384, N=H, K=H
    gemm_nt<<<dim3(kH / BN, (kB * kT) / BM, 1), 256, 0, stream>>>(
        output, kH, 0, attn_w, kH, 0, q, kH, 0, kH);

    // 2) logits = q @ context^T per batch : M=T, N=S, K=H  -> attn region
    gemm_nt<<<dim3(kS / BN, kT / BM, kB), 256, 0, stream>>>(
        q, kH, (long)kT * kH, context, kH, (long)kS * kH,
        attn, kS, (long)kT * kS, kH);

    // 3) softmax over S, in place
    softmax_rows<<<kB * kT, 256, 0, stream>>>(attn);

    // 4) mix = attn @ context per batch : M=T, N=H, K=S
    gemm_nn<<<dim3(kH / BN, kT / BM, kB), 256, 0, stream>>>(
        attn, kS, (long)kT * kS, context, kH, (long)kS * kH,
        mix, kH, (long)kT * kH, kS);

    // 5) out = tanh([mix|q] @ lw^T + lb) : M=B*T, N=H, K=2H
    gemm_out<<<dim3(kH / BN, (kB * kT) / BM, 1), 256, 0, stream>>>(
        mix, q, lw, lb, out);
}

// Round 2
// 1111.350 us; speedup vs baseline: 2.7739x; 2.7739x over previous
//
#include <hip/hip_runtime.h>
#include <math.h>

typedef short bf16x8 __attribute__((ext_vector_type(8)));
typedef float f32x4 __attribute__((ext_vector_type(4)));
typedef unsigned short u16;

constexpr int kB = 16, kT = 1024, kS = 2048, kH = 1024;

// ---------------- bf16 helpers ----------------
__device__ __forceinline__ u16 bf16_rne(float x) {
    unsigned u = __float_as_uint(x);
    u += 0x7FFFu + ((u >> 16) & 1u);
    return (u16)(u >> 16);
}
__device__ __forceinline__ float bf16_f32(u16 h) {
    return __uint_as_float(((unsigned)h) << 16);
}
__device__ __forceinline__ void split2(float x, u16& hi, u16& lo) {
    hi = bf16_rne(x);
    lo = bf16_rne(x - bf16_f32(hi));
}

// ---------------- staging helpers (tile = 128 rows x 32 cols) ----------------
// fp32 global -> split bf16 hi/lo LDS
__device__ __forceinline__ void stage_split(const float* __restrict__ g, int ld, int t,
                                            u16* hiB, u16* loB) {
#pragma unroll
    for (int it = 0; it < 4; ++it) {
        int idx = it * 256 + t;
        int row = idx >> 3;
        int c4  = (idx & 7) << 2;
        float4 v = *(const float4*)(g + (long)row * ld + c4);
        u16 h0,l0,h1,l1,h2,l2,h3,l3;
        split2(v.x, h0, l0); split2(v.y, h1, l1);
        split2(v.z, h2, l2); split2(v.w, h3, l3);
        *(ushort4*)(hiB + row * 32 + c4) = make_ushort4(h0, h1, h2, h3);
        *(ushort4*)(loB + row * 32 + c4) = make_ushort4(l0, l1, l2, l3);
    }
}
// fp32 global -> bf16 LDS (round-to-nearest only)
__device__ __forceinline__ void stage_cvt(const float* __restrict__ g, int ld, int t, u16* dst) {
#pragma unroll
    for (int it = 0; it < 4; ++it) {
        int idx = it * 256 + t;
        int row = idx >> 3;
        int c4  = (idx & 7) << 2;
        float4 v = *(const float4*)(g + (long)row * ld + c4);
        *(ushort4*)(dst + row * 32 + c4) =
            make_ushort4(bf16_rne(v.x), bf16_rne(v.y), bf16_rne(v.z), bf16_rne(v.w));
    }
}
// bf16 global -> bf16 LDS (16B chunks)
__device__ __forceinline__ void stage_bf16(const u16* __restrict__ g, int ld, int t, u16* dst) {
#pragma unroll
    for (int it = 0; it < 2; ++it) {
        int idx = it * 256 + t;
        int row = idx >> 2;
        int c8  = (idx & 3) << 3;
        *(uint4*)(dst + row * 32 + c8) = *(const uint4*)(g + (long)row * ld + c8);
    }
}

// ---------------- MFMA inner compute ----------------
// Wave computes 64x64: 4x4 tiles of 16x16, A/B frag: lane holds X[idx&15][quad*8+j]
__device__ __forceinline__ void mma_plain(const u16* As, const u16* Bs, f32x4 acc[4][4],
                                          int wr, int wc, int l15, int quad) {
    bf16x8 a[4], b[4];
#pragma unroll
    for (int i = 0; i < 4; ++i)
        a[i] = *(const bf16x8*)(As + (wr * 64 + i * 16 + l15) * 32 + quad * 8);
#pragma unroll
    for (int j = 0; j < 4; ++j)
        b[j] = *(const bf16x8*)(Bs + (wc * 64 + j * 16 + l15) * 32 + quad * 8);
#pragma unroll
    for (int i = 0; i < 4; ++i)
#pragma unroll
        for (int j = 0; j < 4; ++j)
            acc[i][j] = __builtin_amdgcn_mfma_f32_16x16x32_bf16(a[i], b[j], acc[i][j], 0, 0, 0);
}

__device__ __forceinline__ void mma_split(const u16* Ah, const u16* Al,
                                          const u16* Bh, const u16* Bl, f32x4 acc[4][4],
                                          int wr, int wc, int l15, int quad) {
    bf16x8 ah[4], al[4], bh[4], bl[4];
#pragma unroll
    for (int i = 0; i < 4; ++i) {
        int off = (wr * 64 + i * 16 + l15) * 32 + quad * 8;
        ah[i] = *(const bf16x8*)(Ah + off);
        al[i] = *(const bf16x8*)(Al + off);
    }
#pragma unroll
    for (int j = 0; j < 4; ++j) {
        int off = (wc * 64 + j * 16 + l15) * 32 + quad * 8;
        bh[j] = *(const bf16x8*)(Bh + off);
        bl[j] = *(const bf16x8*)(Bl + off);
    }
#pragma unroll
    for (int i = 0; i < 4; ++i)
#pragma unroll
        for (int j = 0; j < 4; ++j) {
            acc[i][j] = __builtin_amdgcn_mfma_f32_16x16x32_bf16(ah[i], bh[j], acc[i][j], 0, 0, 0);
            acc[i][j] = __builtin_amdgcn_mfma_f32_16x16x32_bf16(ah[i], bl[j], acc[i][j], 0, 0, 0);
            acc[i][j] = __builtin_amdgcn_mfma_f32_16x16x32_bf16(al[i], bh[j], acc[i][j], 0, 0, 0);
        }
}

// ---------------- ctx transpose+convert: [B,S,H] fp32 -> [B,H,S] bf16 ----------------
__global__ __launch_bounds__(256) void transpose_ctx(const float* __restrict__ ctx,
                                                     u16* __restrict__ ctxT) {
    __shared__ u16 tile[64 * 72];  // [h][s], pitch 72 (16B-aligned rows)
    const int t = threadIdx.x;
    const float* src = ctx + (long)blockIdx.z * kS * kH + (long)(blockIdx.y * 64) * kH
                       + blockIdx.x * 64;
#pragma unroll
    for (int it = 0; it < 4; ++it) {
        int idx = it * 256 + t;              // 1024 float4 chunks = 64 s-rows x 16
        int s = idx >> 4, hq = (idx & 15) << 2;
        float4 v = *(const float4*)(src + (long)s * kH + hq);
        tile[(hq + 0) * 72 + s] = bf16_rne(v.x);
        tile[(hq + 1) * 72 + s] = bf16_rne(v.y);
        tile[(hq + 2) * 72 + s] = bf16_rne(v.z);
        tile[(hq + 3) * 72 + s] = bf16_rne(v.w);
    }
    __syncthreads();
    u16* dst = ctxT + (long)blockIdx.z * kH * kS + (long)(blockIdx.x * 64) * kS
               + blockIdx.y * 64;
#pragma unroll
    for (int it = 0; it < 2; ++it) {
        int idx = it * 256 + t;              // 512 8-u16 chunks = 64 h-rows x 8
        int h = idx >> 3, sq = (idx & 7) << 3;
        *(uint4*)(dst + (long)h * kS + sq) = *(const uint4*)&tile[h * 72 + sq];
    }
}

// ---------------- GEMM1: q = output @ attn_w^T  (split-split, split epilogue) ----------
__global__ __launch_bounds__(256) void gemm_q(const float* __restrict__ A,
                                              const float* __restrict__ Bw,
                                              u16* __restrict__ Qhi, u16* __restrict__ Qlo) {
    __shared__ u16 Ah[128 * 32], Al[128 * 32], Bh[128 * 32], Bl[128 * 32];
    const int t = threadIdx.x, lane = t & 63, wave = t >> 6;
    const int wr = wave >> 1, wc = wave & 1, l15 = lane & 15, quad = lane >> 4;
    const long bm = blockIdx.y * 128, bn = blockIdx.x * 128;

    f32x4 acc[4][4] = {};
    for (int k0 = 0; k0 < kH; k0 += 32) {
        stage_split(A + bm * kH + k0, kH, t, Ah, Al);
        stage_split(Bw + bn * kH + k0, kH, t, Bh, Bl);
        __syncthreads();
        mma_split(Ah, Al, Bh, Bl, acc, wr, wc, l15, quad);
        __syncthreads();
    }
#pragma unroll
    for (int i = 0; i < 4; ++i)
#pragma unroll
        for (int j = 0; j < 4; ++j)
#pragma unroll
            for (int r = 0; r < 4; ++r) {
                long m = bm + wr * 64 + i * 16 + quad * 4 + r;
                long n = bn + wc * 64 + j * 16 + l15;
                float v = acc[i][j][r];
                u16 h = bf16_rne(v);
                Qhi[m * kH + n] = h;
                Qlo[m * kH + n] = bf16_rne(v - bf16_f32(h));
            }
}

// ---------------- GEMM2: logits = q @ ctx^T per batch (split-split) ----------------
__global__ __launch_bounds__(256) void gemm_logits(const u16* __restrict__ Qhi,
                                                   const u16* __restrict__ Qlo,
                                                   const float* __restrict__ ctx,
                                                   float* __restrict__ Cout) {
    __shared__ u16 Ah[128 * 32], Al[128 * 32], Bh[128 * 32], Bl[128 * 32];
    const int t = threadIdx.x, lane = t & 63, wave = t >> 6;
    const int wr = wave >> 1, wc = wave & 1, l15 = lane & 15, quad = lane >> 4;
    const int z = blockIdx.z;
    const long bm = blockIdx.y * 128, bn = blockIdx.x * 128;
    const u16* qh = Qhi + (long)z * kT * kH;
    const u16* ql = Qlo + (long)z * kT * kH;
    const float* cx = ctx + (long)z * kS * kH;
    float* C = Cout + (long)z * kT * kS;

    f32x4 acc[4][4] = {};
    for (int k0 = 0; k0 < kH; k0 += 32) {
        stage_bf16(qh + bm * kH + k0, kH, t, Ah);
        stage_bf16(ql + bm * kH + k0, kH, t, Al);
        stage_split(cx + bn * kH + k0, kH, t, Bh, Bl);
        __syncthreads();
        mma_split(Ah, Al, Bh, Bl, acc, wr, wc, l15, quad);
        __syncthreads();
    }
#pragma unroll
    for (int i = 0; i < 4; ++i)
#pragma unroll
        for (int j = 0; j < 4; ++j)
#pragma unroll
            for (int r = 0; r < 4; ++r) {
                long m = bm + wr * 64 + i * 16 + quad * 4 + r;
                long n = bn + wc * 64 + j * 16 + l15;
                C[m * kS + n] = acc[i][j][r];
            }
}

// ---------------- softmax over S, in place ----------------
__global__ __launch_bounds__(256) void softmax_rows(float* __restrict__ P) {
    __shared__ float red[4];
    float* p = P + (long)blockIdx.x * kS;
    const int t = threadIdx.x;

    float4 v0 = ((const float4*)p)[t];
    float4 v1 = ((const float4*)p)[t + 256];

    float m = fmaxf(fmaxf(fmaxf(v0.x, v0.y), fmaxf(v0.z, v0.w)),
                    fmaxf(fmaxf(v1.x, v1.y), fmaxf(v1.z, v1.w)));
#pragma unroll
    for (int o = 32; o > 0; o >>= 1) m = fmaxf(m, __shfl_xor(m, o));
    if ((t & 63) == 0) red[t >> 6] = m;
    __syncthreads();
    m = fmaxf(fmaxf(red[0], red[1]), fmaxf(red[2], red[3]));
    __syncthreads();

    v0.x = expf(v0.x - m); v0.y = expf(v0.y - m);
    v0.z = expf(v0.z - m); v0.w = expf(v0.w - m);
    v1.x = expf(v1.x - m); v1.y = expf(v1.y - m);
    v1.z = expf(v1.z - m); v1.w = expf(v1.w - m);

    float s = v0.x + v0.y + v0.z + v0.w + v1.x + v1.y + v1.z + v1.w;
#pragma unroll
    for (int o = 32; o > 0; o >>= 1) s += __shfl_xor(s, o);
    if ((t & 63) == 0) red[t >> 6] = s;
    __syncthreads();
    s = red[0] + red[1] + red[2] + red[3];

    const float inv = 1.0f / s;
    v0.x *= inv; v0.y *= inv; v0.z *= inv; v0.w *= inv;
    v1.x *= inv; v1.y *= inv; v1.z *= inv; v1.w *= inv;

    ((float4*)p)[t]       = v0;
    ((float4*)p)[t + 256] = v1;
}

// ---------------- GEMM4: mix = attn @ ctx per batch (bf16, bf16 epilogue) ----------
__global__ __launch_bounds__(256) void gemm_mix(const float* __restrict__ attn,
                                                const u16* __restrict__ ctxT,
                                                u16* __restrict__ Mixb) {
    __shared__ u16 As[128 * 32], Bs[128 * 32];
    const int t = threadIdx.x, lane = t & 63, wave = t >> 6;
    const int wr = wave >> 1, wc = wave & 1, l15 = lane & 15, quad = lane >> 4;
    const int z = blockIdx.z;
    const long bm = blockIdx.y * 128, bn = blockIdx.x * 128;
    const float* Ab = attn + (long)z * kT * kS;
    const u16* Bb = ctxT + (long)z * kH * kS;
    u16* C = Mixb + (long)z * kT * kH;

    f32x4 acc[4][4] = {};
    for (int k0 = 0; k0 < kS; k0 += 32) {
        stage_cvt(Ab + bm * kS + k0, kS, t, As);
        stage_bf16(Bb + bn * kS + k0, kS, t, Bs);
        __syncthreads();
        mma_plain(As, Bs, acc, wr, wc, l15, quad);
        __syncthreads();
    }
#pragma unroll
    for (int i = 0; i < 4; ++i)
#pragma unroll
        for (int j = 0; j < 4; ++j)
#pragma unroll
            for (int r = 0; r < 4; ++r) {
                long m = bm + wr * 64 + i * 16 + quad * 4 + r;
                long n = bn + wc * 64 + j * 16 + l15;
                C[m * kH + n] = bf16_rne(acc[i][j][r]);
            }
}

// ---------------- GEMM5: out = tanh([mix|q] @ lw^T + lb) ----------------
__global__ __launch_bounds__(256) void gemm_out(const u16* __restrict__ Mixb,
                                                const u16* __restrict__ Qhi,
                                                const float* __restrict__ W,
                                                const float* __restrict__ bias,
                                                float* __restrict__ Out) {
    __shared__ u16 As[128 * 32], Bs[128 * 32];
    const int t = threadIdx.x, lane = t & 63, wave = t >> 6;
    const int wr = wave >> 1, wc = wave & 1, l15 = lane & 15, quad = lane >> 4;
    const long bm = blockIdx.y * 128, bn = blockIdx.x * 128;

    f32x4 acc[4][4] = {};
    for (int k0 = 0; k0 < 2 * kH; k0 += 32) {
        const u16* Ab = (k0 < kH) ? (Mixb + bm * kH + k0) : (Qhi + bm * kH + (k0 - kH));
        stage_bf16(Ab, kH, t, As);
        stage_cvt(W + bn * (2 * kH) + k0, 2 * kH, t, Bs);
        __syncthreads();
        mma_plain(As, Bs, acc, wr, wc, l15, quad);
        __syncthreads();
    }
#pragma unroll
    for (int j = 0; j < 4; ++j) {
        long n = bn + wc * 64 + j * 16 + l15;
        float bj = bias[n];
#pragma unroll
        for (int i = 0; i < 4; ++i)
#pragma unroll
            for (int r = 0; r < 4; ++r) {
                long m = bm + wr * 64 + i * 16 + quad * 4 + r;
                Out[m * kH + n] = tanhf(acc[i][j][r] + bj);
            }
    }
}

// ---------------------------------------------------------------------------
extern "C" void kernel_launch(void* const* d_in, const int* in_sizes, int n_in,
                              void* d_out, int out_size, void* d_ws, size_t ws_size,
                              hipStream_t stream) {
    (void)in_sizes; (void)n_in; (void)out_size; (void)ws_size;

    const float* outp = (const float*)d_in[0];  // [B,T,H]
    const float* ctx  = (const float*)d_in[1];  // [B,S,H]
    const float* aw   = (const float*)d_in[2];  // [H,H]
    const float* lw   = (const float*)d_in[3];  // [H,2H]
    const float* lb   = (const float*)d_in[4];  // [H]

    float* out  = (float*)d_out;                          // [B,T,H]
    float* attn = out + (size_t)kB * kT * kH;             // [B,T,S]

    // ws layout (exactly 128 MiB):
    //   q_hi [16.8M u16] | q_lo [16.8M u16] | ctxT [33.6M u16]
    // q_lo is dead after gemm_logits -> reused as mix_bf16.
    u16* q_hi = (u16*)d_ws;
    u16* q_lo = q_hi + (size_t)kB * kT * kH;
    u16* ctxT = q_lo + (size_t)kB * kT * kH;
    u16* mixb = q_lo;

    transpose_ctx<<<dim3(kH / 64, kS / 64, kB), 256, 0, stream>>>(ctx, ctxT);
    gemm_q<<<dim3(kH / 128, (kB * kT) / 128), 256, 0, stream>>>(outp, aw, q_hi, q_lo);
    gemm_logits<<<dim3(kS / 128, kT / 128, kB), 256, 0, stream>>>(q_hi, q_lo, ctx, attn);
    softmax_rows<<<kB * kT, 256, 0, stream>>>(attn);
    gemm_mix<<<dim3(kH / 128, kT / 128, kB), 256, 0, stream>>>(attn, ctxT, mixb);
    gemm_out<<<dim3(kH / 128, (kB * kT) / 128), 256, 0, stream>>>(mixb, q_hi, lw, lb, out);
}